// Round 10
// baseline (722.933 us; speedup 1.0000x reference)
//
#include <hip/hip_runtime.h>

#define NODES 40000
#define EDGES 640000

typedef float f32x2v __attribute__((ext_vector_type(2)));
typedef float f32x4v __attribute__((ext_vector_type(4)));
typedef short short8v __attribute__((ext_vector_type(8)));

__device__ __forceinline__ float silu_f(float x) { return x / (1.0f + __expf(-x)); }
__device__ __forceinline__ f32x2v mk2(float a, float b) { f32x2v r; r[0] = a; r[1] = b; return r; }

// ---------------------------------------------------------------------------
// tp_uuu split by path range (bit-identical to validated tp_uuu2 — verified
// r8: absmax unchanged). paths 0-7 use cols 0-63; paths 8-14 use cols 64-119.
// v: [y,z,x] ; t: [xy,yz,z2,xz,x2y2]
// ---------------------------------------------------------------------------
__device__ __forceinline__ void tp_paths07(const f32x2v* wv,
        f32x2v as, const f32x2v* av, const f32x2v* at,
        f32x2v bs, const f32x2v* bv, const f32x2v* bt,
        f32x2v& os, f32x2v* ov, f32x2v* ot)
{
    const float CR = 0.70710678f;
    const float K1 = 0.31622777f;
    const float K3 = 0.54772256f;

    os += wv[0] * as * bs;
    ov[0] += wv[1] * as * bv[0]; ov[1] += wv[1] * as * bv[1]; ov[2] += wv[1] * as * bv[2];
    ot[0] += wv[2] * as * bt[0]; ot[1] += wv[2] * as * bt[1]; ot[2] += wv[2] * as * bt[2];
    ot[3] += wv[2] * as * bt[3]; ot[4] += wv[2] * as * bt[4];
    ov[0] += wv[3] * av[0] * bs; ov[1] += wv[3] * av[1] * bs; ov[2] += wv[3] * av[2] * bs;
    os += wv[4] * (-0.57735027f) * (av[0]*bv[0] + av[1]*bv[1] + av[2]*bv[2]);
    ov[0] += wv[5] * CR * (av[1]*bv[2] - av[2]*bv[1]);
    ov[1] += wv[5] * CR * (av[2]*bv[0] - av[0]*bv[2]);
    ov[2] += wv[5] * CR * (av[0]*bv[1] - av[1]*bv[0]);
    ot[0] += wv[6] * CR * (av[2]*bv[0] + av[0]*bv[2]);
    ot[1] += wv[6] * CR * (av[0]*bv[1] + av[1]*bv[0]);
    ot[2] += wv[6] * 0.40824829f * (2.f*av[1]*bv[1] - av[2]*bv[2] - av[0]*bv[0]);
    ot[3] += wv[6] * CR * (av[2]*bv[1] + av[1]*bv[2]);
    ot[4] += wv[6] * CR * (av[2]*bv[2] - av[0]*bv[0]);
    ov[0] += wv[7] * (-K3*av[1]*bt[1] + K1*av[0]*bt[2] - K3*av[2]*bt[0] + K3*av[0]*bt[4]);
    ov[1] += wv[7] * (-2.f*K1*av[1]*bt[2] - K3*av[2]*bt[3] - K3*av[0]*bt[1]);
    ov[2] += wv[7] * (-K3*av[1]*bt[3] + K1*av[2]*bt[2] - K3*av[0]*bt[0] - K3*av[2]*bt[4]);
}

__device__ __forceinline__ void tp_paths814(const f32x2v* wv,   // wv[0..6] = paths 8..14
        const f32x2v* av, const f32x2v* at,
        f32x2v bs, const f32x2v* bv, const f32x2v* bt,
        f32x2v& os, f32x2v* ov, f32x2v* ot)
{
    const float K1 = 0.31622777f;
    const float K3 = 0.54772256f;
    const float KA = 0.40824829f;
    const float KB = 0.70710678f;
    const float KC = 0.81649658f;
    const float L4 = 0.63245553f;
    const float G2 = 0.53452248f;
    const float G1 = 0.26726124f;
    const float HH = 0.46291005f;

    ot[0] += wv[0] * ( KC*av[1]*bt[4] - KA*av[2]*bt[3] + KA*av[0]*bt[1]);
    ot[1] += wv[0] * ( KA*av[1]*bt[3] - KB*av[2]*bt[2] - KA*av[0]*bt[0] - KA*av[2]*bt[4]);
    ot[2] += wv[0] * ( KB*av[2]*bt[1] - KB*av[0]*bt[3]);
    ot[3] += wv[0] * (-KA*av[1]*bt[1] + KB*av[0]*bt[2] + KA*av[2]*bt[0] - KA*av[0]*bt[4]);
    ot[4] += wv[0] * (-KC*av[1]*bt[0] + KA*av[2]*bt[1] + KA*av[0]*bt[3]);
    ot[0] += wv[1] * at[0] * bs; ot[1] += wv[1] * at[1] * bs; ot[2] += wv[1] * at[2] * bs;
    ot[3] += wv[1] * at[3] * bs; ot[4] += wv[1] * at[4] * bs;
    ov[0] += wv[2] * (-K3*bv[1]*at[1] + K1*bv[0]*at[2] - K3*bv[2]*at[0] + K3*bv[0]*at[4]);
    ov[1] += wv[2] * (-2.f*K1*bv[1]*at[2] - K3*bv[2]*at[3] - K3*bv[0]*at[1]);
    ov[2] += wv[2] * (-K3*bv[1]*at[3] + K1*bv[2]*at[2] - K3*bv[0]*at[0] - K3*bv[2]*at[4]);
    ot[0] -= wv[3] * ( KC*bv[1]*at[4] - KA*bv[2]*at[3] + KA*bv[0]*at[1]);
    ot[1] -= wv[3] * ( KA*bv[1]*at[3] - KB*bv[2]*at[2] - KA*bv[0]*at[0] - KA*bv[2]*at[4]);
    ot[2] -= wv[3] * ( KB*bv[2]*at[1] - KB*bv[0]*at[3]);
    ot[3] -= wv[3] * (-KA*bv[1]*at[1] + KB*bv[0]*at[2] + KA*bv[2]*at[0] - KA*bv[0]*at[4]);
    ot[4] -= wv[3] * (-KC*bv[1]*at[0] + KA*bv[2]*at[1] + KA*bv[0]*at[3]);
    os += wv[4] * 0.44721360f * (at[0]*bt[0] + at[1]*bt[1] + at[2]*bt[2] + at[3]*bt[3] + at[4]*bt[4]);
    ov[0] += wv[5] * ( K1*(at[0]*bt[1] - at[1]*bt[0]) + K3*(at[3]*bt[2] - at[2]*bt[3]) + K1*(at[4]*bt[3] - at[3]*bt[4]) );
    ov[1] += wv[5] * ( L4*(at[0]*bt[4] - at[4]*bt[0]) + K1*(at[1]*bt[3] - at[3]*bt[1]) );
    ov[2] += wv[5] * ( K1*(at[3]*bt[0] - at[0]*bt[3]) + K3*(at[2]*bt[1] - at[1]*bt[2]) + K1*(at[4]*bt[1] - at[1]*bt[4]) );
    ot[0] += wv[6] * ( G2*(at[2]*bt[0] + at[0]*bt[2]) - HH*(at[1]*bt[3] + at[3]*bt[1]) );
    ot[1] += wv[6] * (-HH*(at[3]*bt[0] + at[0]*bt[3]) + HH*(at[1]*bt[4] + at[4]*bt[1]) - G1*(at[2]*bt[1] + at[1]*bt[2]) );
    ot[2] += wv[6] * ( G2*(at[0]*bt[0] + at[4]*bt[4] - at[2]*bt[2]) - G1*(at[1]*bt[1] + at[3]*bt[3]) );
    ot[3] += wv[6] * (-HH*(at[1]*bt[0] + at[0]*bt[1]) - HH*(at[3]*bt[4] + at[4]*bt[3]) - G1*(at[2]*bt[3] + at[3]*bt[2]) );
    ot[4] += wv[6] * ( G2*(at[2]*bt[4] + at[4]*bt[2]) + HH*(at[1]*bt[1] - at[3]*bt[3]) );
}

// ---------------------------------------------------------------------------
// CSR construction + fused permutation (slot order = dst-sorted).
// srcs PACKS src|dst<<16 (NODES=40000 < 2^16).
// ---------------------------------------------------------------------------
__global__ void deg_kernel(const int* __restrict__ eidx, int* __restrict__ deg)
{
    int e = blockIdx.x * 256 + threadIdx.x;
    if (e < EDGES) atomicAdd(&deg[eidx[EDGES + e]], 1);
}

__launch_bounds__(1024)
__global__ void scan_kernel(const int* __restrict__ deg, int* __restrict__ off,
                            int* __restrict__ cursor)
{
    __shared__ int part[1024];
    const int t = threadIdx.x;
    const int base = t * 40;     // threads 0..999 cover exactly 40000
    int v[40];
    if (t < 1000) {
        const int4* p4 = (const int4*)(deg + base);
        #pragma unroll
        for (int i = 0; i < 10; ++i) {
            int4 q = p4[i];
            v[4 * i + 0] = q.x; v[4 * i + 1] = q.y;
            v[4 * i + 2] = q.z; v[4 * i + 3] = q.w;
        }
    } else {
        #pragma unroll
        for (int i = 0; i < 40; ++i) v[i] = 0;
    }
    int loc[40];
    int s = 0;
    #pragma unroll
    for (int i = 0; i < 40; ++i) { loc[i] = s; s += v[i]; }
    part[t] = s;
    __syncthreads();
    for (int d = 1; d < 1024; d <<= 1) {
        int vv = (t >= d) ? part[t - d] : 0;
        __syncthreads();
        part[t] += vv;
        __syncthreads();
    }
    int tb = (t == 0) ? 0 : part[t - 1];
    if (t < 1000) {
        #pragma unroll
        for (int i = 0; i < 40; ++i) {
            off[base + i] = tb + loc[i];
            cursor[base + i] = tb + loc[i];
        }
    }
    if (t == 1023) off[NODES] = part[1023];
}

// build + permute fused: scatter packed src|dst and evp into CSR slot order
__global__ void build_kernel(const int* __restrict__ eidx, const float* __restrict__ ev,
                             int* __restrict__ cursor,
                             float* __restrict__ evp, int* __restrict__ srcs)
{
    int e = blockIdx.x * 256 + threadIdx.x;
    if (e < EDGES) {
        int dst = eidx[EDGES + e];
        int p = atomicAdd(&cursor[dst], 1);
        srcs[p] = (int)(((unsigned)eidx[e]) | ((unsigned)dst << 16));
        evp[p * 3 + 0] = ev[e * 3 + 0];
        evp[p * 3 + 1] = ev[e * 3 + 1];
        evp[p * 3 + 2] = ev[e * 3 + 2];
    }
}

// ---------------------------------------------------------------------------
// Layer 0: COMPACT output (r6-proven). me[i] = (wacc[p]*hs)*sh[i] is rank-1,
// so write only 24 floats per edge; consumers rebuild bit-identically.
// ---------------------------------------------------------------------------
__launch_bounds__(256, 3)
__global__ void layer0_edge(const float* __restrict__ evp, const int* __restrict__ srcs,
                            const int* __restrict__ xs, const float* __restrict__ embw,
                            const float* __restrict__ w1, const float* __restrict__ b1,
                            const float* __restrict__ w2, const float* __restrict__ b2,
                            float* __restrict__ mbuf)
{
    __shared__ float emb_s[128 * 17];
    __shared__ float hid_s[128 * 68];
    __shared__ float w2t[24 * 68];
    const int tid = threadIdx.x;
    const int e0 = blockIdx.x * 128;

    for (int idx = tid; idx < 64 * 24; idx += 256) {
        int j = idx / 24, o = idx - j * 24;
        w2t[o * 68 + j] = w2[idx];
    }
    for (int idx = tid; idx < 2048; idx += 256) {
        int e = idx >> 4, i = idx & 15;
        const float* ep = evp + (size_t)(e0 + e) * 3;
        float ex = ep[0], ey = ep[1], ez = ep[2];
        float r = sqrtf(ex * ex + ey * ey + ez * ez + 1e-12f);
        float d = r * (17.0f / 3.0f) - (float)(i + 1);
        float f = 0.0f;
        if (fabsf(d) < 1.0f) f = 8.433572869f * __expf(-2.0f / (1.0f - d * d));
        emb_s[e * 17 + i] = f;
    }
    __syncthreads();

    {
        const int egp = tid >> 3;
        const int jb = (tid & 7) * 8;
        float acc2[4][8];
        #pragma unroll
        for (int el = 0; el < 4; ++el)
            #pragma unroll
            for (int k = 0; k < 8; ++k) acc2[el][k] = b1[jb + k];
        #pragma unroll
        for (int i = 0; i < 16; ++i) {
            float4 wa = *(const float4*)&w1[i * 64 + jb];
            float4 wb = *(const float4*)&w1[i * 64 + jb + 4];
            #pragma unroll
            for (int el = 0; el < 4; ++el) {
                float evv = emb_s[(egp * 4 + el) * 17 + i];
                acc2[el][0] += evv * wa.x; acc2[el][1] += evv * wa.y;
                acc2[el][2] += evv * wa.z; acc2[el][3] += evv * wa.w;
                acc2[el][4] += evv * wb.x; acc2[el][5] += evv * wb.y;
                acc2[el][6] += evv * wb.z; acc2[el][7] += evv * wb.w;
            }
        }
        #pragma unroll
        for (int el = 0; el < 4; ++el)
            #pragma unroll
            for (int k = 0; k < 8; ++k)
                hid_s[(egp * 4 + el) * 68 + jb + k] = silu_f(acc2[el][k]);
    }
    __syncthreads();

    const int c = tid & 7, g = (tid >> 3) & 7, wv_ = tid >> 6;
    float wacc[3][4];
    #pragma unroll
    for (int p = 0; p < 3; ++p) {
        float bb = b2[p * 8 + c];
        #pragma unroll
        for (int q = 0; q < 4; ++q) wacc[p][q] = bb;
    }
    for (int jb = 0; jb < 64; jb += 4) {
        float4 h4[4];
        #pragma unroll
        for (int q = 0; q < 4; ++q)
            h4[q] = *(const float4*)&hid_s[(wv_ * 32 + q * 8 + g) * 68 + jb];
        #pragma unroll
        for (int p = 0; p < 3; ++p) {
            float4 w4 = *(const float4*)&w2t[(p * 8 + c) * 68 + jb];
            #pragma unroll
            for (int q = 0; q < 4; ++q)
                wacc[p][q] += h4[q].x * w4.x + h4[q].y * w4.y + h4[q].z * w4.z + h4[q].w * w4.w;
        }
    }

    const int ebase = wv_ * 32 + g;
    #pragma unroll
    for (int q = 0; q < 4; ++q) {
        const int sl = e0 + ebase + 8 * q;
        const int sn = (int)((unsigned)srcs[sl] & 0xffffu);
        float hs = embw[xs[sn] * 8 + c];
        float* me = mbuf + (size_t)sl * 72;
        me[c]      = wacc[0][q] * hs;
        me[8 + c]  = wacc[1][q] * hs;
        me[16 + c] = wacc[2][q] * hs;
    }
}

// ---------------------------------------------------------------------------
// Layers 1/2 tp_edge: MFMA + half-tile + fused segmented agg, COLUMN-SPLIT
// phase B at 4 blocks/CU. r9 fixes vs r8:
//   (1) NO operand state across barriers: C1 loads operands as scope-locals;
//       C2 RELOADS the h-gather and b-operands (L2-hot). Only os/ov/ot (18
//       VGPR) + bhi/blo (32) survive B-sub1 -> no scratch spill (r8: 144 MB
//       spill traffic at VGPR=64).
//   (2) ws_t stride 72 -> 76 (mod 32 = 12): phase-B b128 writes and wvv
//       reads both <=2-way (free) vs r8's 4-way (5.3M conflicts).
//   Reload race safety: compact-read and writeM touch the same mbuf block,
//   but all 8 channel-threads of an edge are in ONE wave; loads are issued
//   before stores in program order -> wave-ordered, no race (r5-proven).
// LDS: ws_t 19456 + hid_s 16384 + dst_s 264 = 36104 -> 4 blocks/CU.
// ---------------------------------------------------------------------------
__launch_bounds__(256, 4)
__global__ void tp_edge(const float* __restrict__ evp, const int* __restrict__ srcs,
                        const float* __restrict__ h,
                        const float* __restrict__ w1, const float* __restrict__ b1,
                        const float* __restrict__ w2, const float* __restrict__ b2,
                        float* __restrict__ mbuf, float* __restrict__ agg,
                        const int writeM, const int compactB)
{
    __shared__ float ws_t[64 * 76];             // col-half w2-output / m_s spill
    __shared__ unsigned short hid_s[128 * 64];  // bf16 hidden, swizzled
    __shared__ int dst_s[66];
    float* emb_s = ws_t;                        // emb 2176 floats <= 4864

    const int tid = threadIdx.x;
    const int e0 = blockIdx.x * 128;

    // ---- phase A1: soft-onehot embedding ----
    for (int idx = tid; idx < 2048; idx += 256) {
        int e = idx >> 4, i = idx & 15;
        const float* ep = evp + (size_t)(e0 + e) * 3;
        float ex = ep[0], ey = ep[1], ez = ep[2];
        float r = sqrtf(ex * ex + ey * ey + ez * ez + 1e-12f);
        float d = r * (17.0f / 3.0f) - (float)(i + 1);
        float f = 0.0f;
        if (fabsf(d) < 1.0f) f = 8.433572869f * __expf(-2.0f / (1.0f - d * d));
        emb_s[e * 17 + i] = f;
    }
    __syncthreads();

    // ---- phase A2: layer-1 MLP (pk-fp32) -> silu -> bf16(RNE) -> swizzled hid_s ----
    {
        const int egp = tid >> 3;
        const int jb = (tid & 7) * 8;
        f32x2v acc2[2][8];
        #pragma unroll
        for (int pr = 0; pr < 2; ++pr)
            #pragma unroll
            for (int k = 0; k < 8; ++k) { float bb = b1[jb + k]; acc2[pr][k] = mk2(bb, bb); }
        #pragma unroll
        for (int i = 0; i < 16; ++i) {
            float4 wa = *(const float4*)&w1[i * 64 + jb];
            float4 wb = *(const float4*)&w1[i * 64 + jb + 4];
            #pragma unroll
            for (int pr = 0; pr < 2; ++pr) {
                f32x2v evv = mk2(emb_s[(egp * 4 + 2 * pr) * 17 + i],
                                 emb_s[(egp * 4 + 2 * pr + 1) * 17 + i]);
                acc2[pr][0] += evv * wa.x; acc2[pr][1] += evv * wa.y;
                acc2[pr][2] += evv * wa.z; acc2[pr][3] += evv * wa.w;
                acc2[pr][4] += evv * wb.x; acc2[pr][5] += evv * wb.y;
                acc2[pr][6] += evv * wb.z; acc2[pr][7] += evv * wb.w;
            }
        }
        #pragma unroll
        for (int pr = 0; pr < 2; ++pr) {
            #pragma unroll
            for (int u = 0; u < 2; ++u) {
                unsigned int us[8];
                #pragma unroll
                for (int k = 0; k < 8; ++k) {
                    unsigned int b = __float_as_uint(silu_f(acc2[pr][k][u]));
                    b += 0x7fffu + ((b >> 16) & 1u);
                    us[k] = b >> 16;
                }
                uint4 pk;
                pk.x = us[0] | (us[1] << 16);
                pk.y = us[2] | (us[3] << 16);
                pk.z = us[4] | (us[5] << 16);
                pk.w = us[6] | (us[7] << 16);
                int rr = egp * 4 + 2 * pr + u;
                *(uint4*)&hid_s[rr * 64 + (jb ^ ((rr & 7) << 3))] = pk;
            }
        }
    }
    __syncthreads();

    // ---- B-operand fragments: w2 hi/lo bf16 split in-kernel (r6-proven) ----
    const int l  = tid & 63;
    const int wq = tid >> 6;
    const int lr = l & 15;
    const int lg = l >> 4;

    short8v bhi[2][2], blo[2][2];   // [sub][ks]
    #pragma unroll
    for (int sub = 0; sub < 2; ++sub) {
        int col  = 64 * sub + wq * 16 + lr;
        int colc = col < 120 ? col : 119;
        #pragma unroll
        for (int ks = 0; ks < 2; ++ks) {
            short8v hv, lv;
            #pragma unroll
            for (int j = 0; j < 8; ++j) {
                int k = ks * 32 + lg * 8 + j;
                float v = w2[k * 120 + colc];
                if (col >= 120) v = 0.0f;
                unsigned bb = __float_as_uint(v);
                unsigned rh = bb + 0x7fffu + ((bb >> 16) & 1u);
                float hf = __uint_as_float((rh >> 16) << 16);
                unsigned bl = __float_as_uint(v - hf);
                bl += 0x7fffu + ((bl >> 16) & 1u);
                hv[j] = (short)(rh >> 16);
                lv[j] = (short)(bl >> 16);
            }
            bhi[sub][ks] = hv;
            blo[sub][ks] = lv;
        }
    }

    const int c = tid & 7, g = (tid >> 3) & 7, wv_ = tid >> 6;
    const int ebh = wv_ * 16 + g;   // phase-C local edge base, pair +0/+8

    #pragma unroll
    for (int half = 0; half < 2; ++half) {
        const int eA = e0 + 64 * half + ebh;
        const int eB = eA + 8;

        // ---- B sub=0: cols 0-63 -> ws_t rows=col (stride 76) ----
        #pragma unroll
        for (int mm = 0; mm < 4; ++mm) {
            int e  = 64 * half + 16 * mm + lr;
            int sw = (e & 7) << 3;
            short8v a0 = *(const short8v*)&hid_s[e * 64 + ((lg * 8) ^ sw)];
            short8v a1 = *(const short8v*)&hid_s[e * 64 + ((32 + lg * 8) ^ sw)];
            int col = wq * 16 + lr;              // < 64
            float bias = b2[col];
            f32x4v acc;
            acc[0] = bias; acc[1] = bias; acc[2] = bias; acc[3] = bias;
            acc = __builtin_amdgcn_mfma_f32_16x16x32_bf16(a0, bhi[0][0], acc, 0, 0, 0);
            acc = __builtin_amdgcn_mfma_f32_16x16x32_bf16(a1, bhi[0][1], acc, 0, 0, 0);
            acc = __builtin_amdgcn_mfma_f32_16x16x32_bf16(a0, blo[0][0], acc, 0, 0, 0);
            acc = __builtin_amdgcn_mfma_f32_16x16x32_bf16(a1, blo[0][1], acc, 0, 0, 0);
            *(f32x4v*)&ws_t[col * 76 + 16 * mm + lg * 4] = acc;
        }
        __syncthreads();

        // ---- C1: load operands as SCOPE-LOCALS, accumulate paths 0-7 ----
        f32x2v os, ov[3], ot[5];
        {
            const unsigned pkA = (unsigned)srcs[eA], pkB = (unsigned)srcs[eB];
            const int snA = (int)(pkA & 0xffffu), snB = (int)(pkB & 0xffffu);
            const float* hn0 = h + (size_t)snA * 72 + c * 9;
            const float* hn1 = h + (size_t)snB * 72 + c * 9;
            f32x2v as = mk2(hn0[0], hn1[0]);
            f32x2v av[3], at[5], bs, bv[3], bt[5];
            #pragma unroll
            for (int i = 0; i < 3; ++i) av[i] = mk2(hn0[1 + i], hn1[1 + i]);
            #pragma unroll
            for (int i = 0; i < 5; ++i) at[i] = mk2(hn0[4 + i], hn1[4 + i]);

            if (compactB) {
                float w0A = mbuf[(size_t)eA * 72 + c];
                float w1A = mbuf[(size_t)eA * 72 + 8 + c];
                float w2A = mbuf[(size_t)eA * 72 + 16 + c];
                float w0B = mbuf[(size_t)eB * 72 + c];
                float w1B = mbuf[(size_t)eB * 72 + 8 + c];
                float w2B = mbuf[(size_t)eB * 72 + 16 + c];
                const float* epA = evp + (size_t)eA * 3;
                const float* epB = evp + (size_t)eB * 3;
                float exA = epA[0], eyA = epA[1], ezA = epA[2];
                float exB = epB[0], eyB = epB[1], ezB = epB[2];
                float rA = sqrtf(exA * exA + eyA * eyA + ezA * ezA + 1e-12f);
                float rB = sqrtf(exB * exB + eyB * eyB + ezB * ezB + 1e-12f);
                float iA = 1.0f / rA, iB = 1.0f / rB;
                float xA = exA * iA, yA = eyA * iA, zA = ezA * iA;
                float xB = exB * iB, yB = eyB * iB, zB = ezB * iB;
                const float c3 = 1.7320508f, c15 = 3.8729833f, c5 = 2.2360680f;
                bs = mk2(silu_f(w0A), silu_f(w0B));
                bv[0] = mk2(w1A * (c3 * yA), w1B * (c3 * yB));
                bv[1] = mk2(w1A * (c3 * zA), w1B * (c3 * zB));
                bv[2] = mk2(w1A * (c3 * xA), w1B * (c3 * xB));
                bt[0] = mk2(w2A * (c15 * xA * yA), w2B * (c15 * xB * yB));
                bt[1] = mk2(w2A * (c15 * yA * zA), w2B * (c15 * yB * zB));
                bt[2] = mk2(w2A * (0.5f * c5 * (3.f * zA * zA - 1.f)),
                            w2B * (0.5f * c5 * (3.f * zB * zB - 1.f)));
                bt[3] = mk2(w2A * (c15 * xA * zA), w2B * (c15 * xB * zB));
                bt[4] = mk2(w2A * (0.5f * c15 * (xA * xA - yA * yA)),
                            w2B * (0.5f * c15 * (xB * xB - yB * yB)));
            } else {
                const float* me0 = mbuf + (size_t)eA * 72 + c * 9;
                const float* me1 = mbuf + (size_t)eB * 72 + c * 9;
                bs = mk2(silu_f(me0[0]), silu_f(me1[0]));
                #pragma unroll
                for (int i = 0; i < 3; ++i) bv[i] = mk2(me0[1 + i], me1[1 + i]);
                #pragma unroll
                for (int i = 0; i < 5; ++i) bt[i] = mk2(me0[4 + i], me1[4 + i]);
            }

            os = mk2(0.f, 0.f);
            #pragma unroll
            for (int i = 0; i < 3; ++i) ov[i] = mk2(0.f, 0.f);
            #pragma unroll
            for (int i = 0; i < 5; ++i) ot[i] = mk2(0.f, 0.f);

            f32x2v wvv[8];
            #pragma unroll
            for (int p = 0; p < 8; ++p)
                wvv[p] = mk2(ws_t[(p * 8 + c) * 76 + ebh],
                             ws_t[(p * 8 + c) * 76 + ebh + 8]);
            tp_paths07(wvv, as, av, at, bs, bv, bt, os, ov, ot);
        }   // as/av/at/bs/bv/bt dead here -> only os/ov/ot + frags live
        __syncthreads();   // C1 ws_t reads done

        // ---- B sub=1: cols 64-119 -> ws_t rows=col-64 ----
        #pragma unroll
        for (int mm = 0; mm < 4; ++mm) {
            int e  = 64 * half + 16 * mm + lr;
            int sw = (e & 7) << 3;
            short8v a0 = *(const short8v*)&hid_s[e * 64 + ((lg * 8) ^ sw)];
            short8v a1 = *(const short8v*)&hid_s[e * 64 + ((32 + lg * 8) ^ sw)];
            int col = 64 + wq * 16 + lr;
            float bias = (col < 120) ? b2[col] : 0.0f;
            f32x4v acc;
            acc[0] = bias; acc[1] = bias; acc[2] = bias; acc[3] = bias;
            acc = __builtin_amdgcn_mfma_f32_16x16x32_bf16(a0, bhi[1][0], acc, 0, 0, 0);
            acc = __builtin_amdgcn_mfma_f32_16x16x32_bf16(a1, bhi[1][1], acc, 0, 0, 0);
            acc = __builtin_amdgcn_mfma_f32_16x16x32_bf16(a0, blo[1][0], acc, 0, 0, 0);
            acc = __builtin_amdgcn_mfma_f32_16x16x32_bf16(a1, blo[1][1], acc, 0, 0, 0);
            if (col < 120)
                *(f32x4v*)&ws_t[(col - 64) * 76 + 16 * mm + lg * 4] = acc;
        }
        __syncthreads();

        // ---- C2: RELOAD operands (L2-hot), paths 8-14, finalize, writeM ----
        f32x2v ms, mv[3], mt[5];
        {
            const unsigned pkA = (unsigned)srcs[eA], pkB = (unsigned)srcs[eB];
            const int snA = (int)(pkA & 0xffffu), snB = (int)(pkB & 0xffffu);
            const float* hn0 = h + (size_t)snA * 72 + c * 9;
            const float* hn1 = h + (size_t)snB * 72 + c * 9;
            f32x2v av[3], at[5], bs, bv[3], bt[5];
            #pragma unroll
            for (int i = 0; i < 3; ++i) av[i] = mk2(hn0[1 + i], hn1[1 + i]);
            #pragma unroll
            for (int i = 0; i < 5; ++i) at[i] = mk2(hn0[4 + i], hn1[4 + i]);

            if (compactB) {
                float w0A = mbuf[(size_t)eA * 72 + c];
                float w1A = mbuf[(size_t)eA * 72 + 8 + c];
                float w2A = mbuf[(size_t)eA * 72 + 16 + c];
                float w0B = mbuf[(size_t)eB * 72 + c];
                float w1B = mbuf[(size_t)eB * 72 + 8 + c];
                float w2B = mbuf[(size_t)eB * 72 + 16 + c];
                const float* epA = evp + (size_t)eA * 3;
                const float* epB = evp + (size_t)eB * 3;
                float exA = epA[0], eyA = epA[1], ezA = epA[2];
                float exB = epB[0], eyB = epB[1], ezB = epB[2];
                float rA = sqrtf(exA * exA + eyA * eyA + ezA * ezA + 1e-12f);
                float rB = sqrtf(exB * exB + eyB * eyB + ezB * ezB + 1e-12f);
                float iA = 1.0f / rA, iB = 1.0f / rB;
                float xA = exA * iA, yA = eyA * iA, zA = ezA * iA;
                float xB = exB * iB, yB = eyB * iB, zB = ezB * iB;
                const float c3 = 1.7320508f, c15 = 3.8729833f, c5 = 2.2360680f;
                bs = mk2(silu_f(w0A), silu_f(w0B));
                bv[0] = mk2(w1A * (c3 * yA), w1B * (c3 * yB));
                bv[1] = mk2(w1A * (c3 * zA), w1B * (c3 * zB));
                bv[2] = mk2(w1A * (c3 * xA), w1B * (c3 * xB));
                bt[0] = mk2(w2A * (c15 * xA * yA), w2B * (c15 * xB * yB));
                bt[1] = mk2(w2A * (c15 * yA * zA), w2B * (c15 * yB * zB));
                bt[2] = mk2(w2A * (0.5f * c5 * (3.f * zA * zA - 1.f)),
                            w2B * (0.5f * c5 * (3.f * zB * zB - 1.f)));
                bt[3] = mk2(w2A * (c15 * xA * zA), w2B * (c15 * xB * zB));
                bt[4] = mk2(w2A * (0.5f * c15 * (xA * xA - yA * yA)),
                            w2B * (0.5f * c15 * (xB * xB - yB * yB)));
            } else {
                const float* me0 = mbuf + (size_t)eA * 72 + c * 9;
                const float* me1 = mbuf + (size_t)eB * 72 + c * 9;
                bs = mk2(silu_f(me0[0]), silu_f(me1[0]));
                #pragma unroll
                for (int i = 0; i < 3; ++i) bv[i] = mk2(me0[1 + i], me1[1 + i]);
                #pragma unroll
                for (int i = 0; i < 5; ++i) bt[i] = mk2(me0[4 + i], me1[4 + i]);
            }

            f32x2v wvv[7];
            #pragma unroll
            for (int p = 0; p < 7; ++p)
                wvv[p] = mk2(ws_t[(p * 8 + c) * 76 + ebh],
                             ws_t[(p * 8 + c) * 76 + ebh + 8]);
            tp_paths814(wvv, av, at, bs, bv, bt, os, ov, ot);

            ms = os * 0.57735027f;
            #pragma unroll
            for (int i = 0; i < 3; ++i) mv[i] = ov[i] * 0.40824829f;
            #pragma unroll
            for (int i = 0; i < 5; ++i) mt[i] = ot[i] * 0.40824829f;

            if (writeM) {
                float* mo0 = mbuf + (size_t)eA * 72 + c * 9;
                float* mo1 = mbuf + (size_t)eB * 72 + c * 9;
                mo0[0] = ms[0]; mo1[0] = ms[1];
                #pragma unroll
                for (int i = 0; i < 3; ++i) { mo0[1 + i] = mv[i][0]; mo1[1 + i] = mv[i][1]; }
                #pragma unroll
                for (int i = 0; i < 5; ++i) { mo0[4 + i] = mt[i][0]; mo1[4 + i] = mt[i][1]; }
            }
        }

        // dst window [e0+64h, e0+64h+64]; sentinel past array end
        if (tid <= 64) {
            int gs = e0 + 64 * half + tid;
            dst_s[tid] = (gs < EDGES) ? (int)((unsigned)srcs[gs] >> 16) : -1;
        }
        __syncthreads();   // C2 ws_t reads done + dst_s visible -> ws_t reusable

        // spill m into m_s[64][76] (ws_t region)
        float* m_s = ws_t;
        const int lA = ebh, lB = ebh + 8;
        m_s[lA * 76 + c * 9] = ms[0]; m_s[lB * 76 + c * 9] = ms[1];
        #pragma unroll
        for (int i = 0; i < 3; ++i) {
            m_s[lA * 76 + c * 9 + 1 + i] = mv[i][0];
            m_s[lB * 76 + c * 9 + 1 + i] = mv[i][1];
        }
        #pragma unroll
        for (int i = 0; i < 5; ++i) {
            m_s[lA * 76 + c * 9 + 4 + i] = mt[i][0];
            m_s[lB * 76 + c * 9 + 4 + i] = mt[i][1];
        }
        __syncthreads();

        // segmented reduce: comp = t%72, 3 slot-subranges, slot order
        if (tid < 216) {
            const int seg  = tid / 72;
            const int comp = tid - seg * 72;
            const int p0 = (seg == 0) ? 0  : ((seg == 1) ? 22 : 43);
            const int p1 = (seg == 0) ? 22 : ((seg == 1) ? 43 : 64);
            float sum = 0.f;
            int cur = dst_s[p0];
            for (int p = p0; p < p1; ++p) {
                sum += m_s[p * 76 + comp];
                int nxt = dst_s[p + 1];
                if (nxt != cur) {
                    atomicAdd(&agg[(size_t)cur * 72 + comp], sum);
                    sum = 0.f; cur = nxt;
                }
            }
            if (cur >= 0) atomicAdd(&agg[(size_t)cur * 72 + comp], sum);
        }
        if (half == 0) __syncthreads();   // m_s reads done before next-half B
    }
}

// ---------------------------------------------------------------------------
// node0: rebuilds layer0's me from the compact record + evp (bit-identical).
// ---------------------------------------------------------------------------
__global__ void node0(const int* __restrict__ xs, const float* __restrict__ embw,
                      const float* __restrict__ lin0, const float* __restrict__ mbuf,
                      const float* __restrict__ evp,
                      const int* __restrict__ off, float* __restrict__ h)
{
    int idx = blockIdx.x * 256 + threadIdx.x;
    int n = idx >> 3, c = idx & 7;
    int xb = xs[n] * 8;
    float dot = 0.f;
    #pragma unroll
    for (int d = 0; d < 8; ++d) dot += embw[xb + d] * lin0[d * 8 + c];

    float an[9];
    #pragma unroll
    for (int i = 0; i < 9; ++i) an[i] = 0.f;
    const float c3 = 1.7320508f, c15 = 3.8729833f, c5 = 2.2360680f;
    const int beg = off[n], end = off[n + 1];
    for (int p = beg; p < end; ++p) {
        float w0 = mbuf[(size_t)p * 72 + c];
        float w1 = mbuf[(size_t)p * 72 + 8 + c];
        float w2 = mbuf[(size_t)p * 72 + 16 + c];
        const float* ep = evp + (size_t)p * 3;
        float ex = ep[0], ey = ep[1], ez = ep[2];
        float r = sqrtf(ex * ex + ey * ey + ez * ez + 1e-12f);
        float inv = 1.0f / r;
        float x = ex * inv, y = ey * inv, z = ez * inv;
        an[0] += w0;
        an[1] += w1 * (c3 * y);
        an[2] += w1 * (c3 * z);
        an[3] += w1 * (c3 * x);
        an[4] += w2 * (c15 * x * y);
        an[5] += w2 * (c15 * y * z);
        an[6] += w2 * (0.5f * c5 * (3.f * z * z - 1.f));
        an[7] += w2 * (c15 * x * z);
        an[8] += w2 * (0.5f * c15 * (x * x - y * y));
    }

    float* hn = h + (size_t)n * 72 + c * 9;
    hn[0] = silu_f(an[0] * 0.25f + dot * 0.35355339f);
    #pragma unroll
    for (int i = 1; i < 9; ++i) hn[i] = an[i] * 0.25f;
}

// reads agg (in-place safe: per-thread reads then writes same 9 floats)
__global__ void node12(const float* __restrict__ hin, const float* __restrict__ lin,
                       const float* __restrict__ agg, float* __restrict__ hout)
{
    int idx = blockIdx.x * 256 + threadIdx.x;
    int n = idx >> 3, d = idx & 7;

    float an[9];
    #pragma unroll
    for (int i = 0; i < 9; ++i) an[i] = agg[(size_t)n * 72 + d * 9 + i];

    const float* hn = hin + (size_t)n * 72;
    float* ho = hout + (size_t)n * 72 + d * 9;

    float s = 0.f;
    #pragma unroll
    for (int c = 0; c < 8; ++c) s += hn[c * 9] * lin[c * 8 + d];
    ho[0] = silu_f(s * 0.35355339f + an[0] * 0.25f);
    #pragma unroll
    for (int i = 0; i < 3; ++i) {
        float v = 0.f;
        #pragma unroll
        for (int c = 0; c < 8; ++c) v += hn[c * 9 + 1 + i] * lin[64 + c * 8 + d];
        ho[1 + i] = v * 0.35355339f + an[1 + i] * 0.25f;
    }
    #pragma unroll
    for (int i = 0; i < 5; ++i) {
        float t = 0.f;
        #pragma unroll
        for (int c = 0; c < 8; ++c) t += hn[c * 9 + 4 + i] * lin[128 + c * 8 + d];
        ho[4 + i] = t * 0.35355339f + an[4 + i] * 0.25f;
    }
}

// Fused final node update + output head, reading agg instead of mbuf scan
__global__ void node12_out(const float* __restrict__ hin, const float* __restrict__ lin,
                           const float* __restrict__ agg,
                           const float* __restrict__ outw, float* __restrict__ out)
{
    __shared__ float hrec[32][72];
    int idx = blockIdx.x * 256 + threadIdx.x;
    int n = idx >> 3, d = idx & 7;
    int nl = threadIdx.x >> 3;

    float an[9];
    #pragma unroll
    for (int i = 0; i < 9; ++i) an[i] = agg[(size_t)n * 72 + d * 9 + i];

    const float* hn = hin + (size_t)n * 72;
    float* ho = &hrec[nl][d * 9];

    float s = 0.f;
    #pragma unroll
    for (int c = 0; c < 8; ++c) s += hn[c * 9] * lin[c * 8 + d];
    ho[0] = silu_f(s * 0.35355339f + an[0] * 0.25f);
    #pragma unroll
    for (int i = 0; i < 3; ++i) {
        float v = 0.f;
        #pragma unroll
        for (int c = 0; c < 8; ++c) v += hn[c * 9 + 1 + i] * lin[64 + c * 8 + d];
        ho[1 + i] = v * 0.35355339f + an[1 + i] * 0.25f;
    }
    #pragma unroll
    for (int i = 0; i < 5; ++i) {
        float t = 0.f;
        #pragma unroll
        for (int c = 0; c < 8; ++c) t += hn[c * 9 + 4 + i] * lin[128 + c * 8 + d];
        ho[4 + i] = t * 0.35355339f + an[4 + i] * 0.25f;
    }
    __syncthreads();

    const float* hr = &hrec[nl][0];
    float sv[8], vv[24], tv[40];
    #pragma unroll
    for (int i = 0; i < 8; ++i) {
        sv[i] = hr[i * 9];
        #pragma unroll
        for (int q = 0; q < 3; ++q) vv[i * 3 + q] = hr[i * 9 + 1 + q];
        #pragma unroll
        for (int q = 0; q < 5; ++q) tv[i * 5 + q] = hr[i * 9 + 4 + q];
    }
    float acc = 0.f;
    #pragma unroll
    for (int i = 0; i < 8; ++i) {
        #pragma unroll
        for (int j = 0; j < 8; ++j) {
            float dv = vv[i*3+0]*vv[j*3+0] + vv[i*3+1]*vv[j*3+1] + vv[i*3+2]*vv[j*3+2];
            float dt = tv[i*5+0]*tv[j*5+0] + tv[i*5+1]*tv[j*5+1] + tv[i*5+2]*tv[j*5+2]
                     + tv[i*5+3]*tv[j*5+3] + tv[i*5+4]*tv[j*5+4];
            int o = (i * 8 + j) * 8 + d;
            acc += sv[i] * sv[j] * outw[o]
                 + dv * 0.57735027f * outw[512 + o]
                 + dt * 0.44721360f * outw[1024 + o];
        }
    }
    out[n * 8 + d] = acc * 0.072168784f;
}

// ---------------------------------------------------------------------------
extern "C" void kernel_launch(void* const* d_in, const int* in_sizes, int n_in,
                              void* d_out, int out_size, void* d_ws, size_t ws_size,
                              hipStream_t stream)
{
    const int*   x    = (const int*)  d_in[0];
    const int*   eidx = (const int*)  d_in[1];
    const float* ev   = (const float*)d_in[2];
    const float* embw = (const float*)d_in[3];
    const float* lin0 = (const float*)d_in[4];
    const float* lin1 = (const float*)d_in[5];
    const float* lin2 = (const float*)d_in[6];
    const float* outw = (const float*)d_in[7];
    const float* r0w1 = (const float*)d_in[8];
    const float* r0b1 = (const float*)d_in[9];
    const float* r0w2 = (const float*)d_in[10];
    const float* r0b2 = (const float*)d_in[11];
    const float* r1w1 = (const float*)d_in[12];
    const float* r1b1 = (const float*)d_in[13];
    const float* r1w2 = (const float*)d_in[14];
    const float* r1b2 = (const float*)d_in[15];
    const float* r2w1 = (const float*)d_in[16];
    const float* r2b1 = (const float*)d_in[17];
    const float* r2w2 = (const float*)d_in[18];
    const float* r2b2 = (const float*)d_in[19];

    float* mbuf = (float*)d_ws;                          // EDGES*72 f32
    float* hA   = mbuf + (size_t)EDGES * 72;             // NODES*72
    float* hB   = hA + (size_t)NODES * 72;               // NODES*72
    float* evp  = hB + (size_t)NODES * 72;               // EDGES*3
    int*   deg    = (int*)(evp + (size_t)EDGES * 3);     // NODES
    int*   off    = deg + NODES;                         // NODES+1
    int*   cursor = off + NODES + 1;                     // NODES
    int*   srcs   = cursor + NODES;                      // EDGES (src|dst<<16)

    const int EBI = (EDGES + 255) / 256;
    const int EB  = EDGES / 128;
    const int NBK = NODES * 8 / 256;
    const size_t HBYTES = (size_t)NODES * 72 * sizeof(float);

    // CSR build + fused permutation
    hipMemsetAsync(deg, 0, NODES * sizeof(int), stream);
    hipMemsetAsync(hB, 0, HBYTES, stream);               // L1 agg target
    deg_kernel<<<EBI, 256, 0, stream>>>(eidx, deg);
    scan_kernel<<<1, 1024, 0, stream>>>(deg, off, cursor);
    build_kernel<<<EBI, 256, 0, stream>>>(eidx, ev, cursor, evp, srcs);

    // Layer 0 (compact m record)
    layer0_edge<<<EB, 256, 0, stream>>>(evp, srcs, x, embw, r0w1, r0b1, r0w2, r0b2, mbuf);
    node0<<<NBK, 256, 0, stream>>>(x, embw, lin0, mbuf, evp, off, hA);

    // Layer 1: compact b-operand; aggregates into hB; node12 transforms in place
    tp_edge<<<EB, 256, 0, stream>>>(evp, srcs, hA, r1w1, r1b1, r1w2, r1b2, mbuf, hB, 1, 1);
    node12<<<NBK, 256, 0, stream>>>(hA, lin1, hB, hB);

    // Layer 2: full-m b-operand; hA dead after node12 -> reuse as agg; no mbuf write
    hipMemsetAsync(hA, 0, HBYTES, stream);
    tp_edge<<<EB, 256, 0, stream>>>(evp, srcs, hB, r2w1, r2b1, r2w2, r2b2, mbuf, hA, 0, 0);
    node12_out<<<NBK, 256, 0, stream>>>(hB, lin2, hA, outw, (float*)d_out);
}

// Round 11
// 666.422 us; speedup vs baseline: 1.0848x; 1.0848x over previous
//
#include <hip/hip_runtime.h>

#define NODES 40000
#define EDGES 640000

typedef float f32x2v __attribute__((ext_vector_type(2)));
typedef float f32x4v __attribute__((ext_vector_type(4)));
typedef short short8v __attribute__((ext_vector_type(8)));

__device__ __forceinline__ float silu_f(float x) { return x / (1.0f + __expf(-x)); }
__device__ __forceinline__ f32x2v mk2(float a, float b) { f32x2v r; r[0] = a; r[1] = b; return r; }

// ---------------------------------------------------------------------------
// Real-basis Clebsch-Gordan contraction, 2 edges packed per call (f32x2v).
// v: [y,z,x] ; t: [xy,yz,z2,xz,x2y2]
// ---------------------------------------------------------------------------
__device__ __forceinline__ void tp_uuu2(const f32x2v* wv,
                                        f32x2v as, const f32x2v* av, const f32x2v* at,
                                        f32x2v bs, const f32x2v* bv, const f32x2v* bt,
                                        f32x2v& ms, f32x2v* mv, f32x2v* mt)
{
    const float CR = 0.70710678f;
    const float K1 = 0.31622777f;
    const float K3 = 0.54772256f;
    const float KA = 0.40824829f;
    const float KB = 0.70710678f;
    const float KC = 0.81649658f;
    const float L4 = 0.63245553f;
    const float G2 = 0.53452248f;
    const float G1 = 0.26726124f;
    const float HH = 0.46291005f;

    f32x2v os = {0.f, 0.f};
    f32x2v ov0 = {0.f, 0.f}, ov1 = {0.f, 0.f}, ov2 = {0.f, 0.f};
    f32x2v ot0 = {0.f, 0.f}, ot1 = {0.f, 0.f}, ot2 = {0.f, 0.f};
    f32x2v ot3 = {0.f, 0.f}, ot4 = {0.f, 0.f};

    os += wv[0] * as * bs;
    ov0 += wv[1] * as * bv[0]; ov1 += wv[1] * as * bv[1]; ov2 += wv[1] * as * bv[2];
    ot0 += wv[2] * as * bt[0]; ot1 += wv[2] * as * bt[1]; ot2 += wv[2] * as * bt[2];
    ot3 += wv[2] * as * bt[3]; ot4 += wv[2] * as * bt[4];
    ov0 += wv[3] * av[0] * bs; ov1 += wv[3] * av[1] * bs; ov2 += wv[3] * av[2] * bs;
    os += wv[4] * (-0.57735027f) * (av[0]*bv[0] + av[1]*bv[1] + av[2]*bv[2]);
    ov0 += wv[5] * CR * (av[1]*bv[2] - av[2]*bv[1]);
    ov1 += wv[5] * CR * (av[2]*bv[0] - av[0]*bv[2]);
    ov2 += wv[5] * CR * (av[0]*bv[1] - av[1]*bv[0]);
    ot0 += wv[6] * CR * (av[2]*bv[0] + av[0]*bv[2]);
    ot1 += wv[6] * CR * (av[0]*bv[1] + av[1]*bv[0]);
    ot2 += wv[6] * 0.40824829f * (2.f*av[1]*bv[1] - av[2]*bv[2] - av[0]*bv[0]);
    ot3 += wv[6] * CR * (av[2]*bv[1] + av[1]*bv[2]);
    ot4 += wv[6] * CR * (av[2]*bv[2] - av[0]*bv[0]);
    ov0 += wv[7] * (-K3*av[1]*bt[1] + K1*av[0]*bt[2] - K3*av[2]*bt[0] + K3*av[0]*bt[4]);
    ov1 += wv[7] * (-2.f*K1*av[1]*bt[2] - K3*av[2]*bt[3] - K3*av[0]*bt[1]);
    ov2 += wv[7] * (-K3*av[1]*bt[3] + K1*av[2]*bt[2] - K3*av[0]*bt[0] - K3*av[2]*bt[4]);
    ot0 += wv[8] * ( KC*av[1]*bt[4] - KA*av[2]*bt[3] + KA*av[0]*bt[1]);
    ot1 += wv[8] * ( KA*av[1]*bt[3] - KB*av[2]*bt[2] - KA*av[0]*bt[0] - KA*av[2]*bt[4]);
    ot2 += wv[8] * ( KB*av[2]*bt[1] - KB*av[0]*bt[3]);
    ot3 += wv[8] * (-KA*av[1]*bt[1] + KB*av[0]*bt[2] + KA*av[2]*bt[0] - KA*av[0]*bt[4]);
    ot4 += wv[8] * (-KC*av[1]*bt[0] + KA*av[2]*bt[1] + KA*av[0]*bt[3]);
    ot0 += wv[9] * at[0] * bs; ot1 += wv[9] * at[1] * bs; ot2 += wv[9] * at[2] * bs;
    ot3 += wv[9] * at[3] * bs; ot4 += wv[9] * at[4] * bs;
    ov0 += wv[10] * (-K3*bv[1]*at[1] + K1*bv[0]*at[2] - K3*bv[2]*at[0] + K3*bv[0]*at[4]);
    ov1 += wv[10] * (-2.f*K1*bv[1]*at[2] - K3*bv[2]*at[3] - K3*bv[0]*at[1]);
    ov2 += wv[10] * (-K3*bv[1]*at[3] + K1*bv[2]*at[2] - K3*bv[0]*at[0] - K3*bv[2]*at[4]);
    ot0 -= wv[11] * ( KC*bv[1]*at[4] - KA*bv[2]*at[3] + KA*bv[0]*at[1]);
    ot1 -= wv[11] * ( KA*bv[1]*at[3] - KB*bv[2]*at[2] - KA*bv[0]*at[0] - KA*bv[2]*at[4]);
    ot2 -= wv[11] * ( KB*bv[2]*at[1] - KB*bv[0]*at[3]);
    ot3 -= wv[11] * (-KA*bv[1]*at[1] + KB*bv[0]*at[2] + KA*bv[2]*at[0] - KA*bv[0]*at[4]);
    ot4 -= wv[11] * (-KC*bv[1]*at[0] + KA*bv[2]*at[1] + KA*bv[0]*at[3]);
    os += wv[12] * 0.44721360f * (at[0]*bt[0] + at[1]*bt[1] + at[2]*bt[2] + at[3]*bt[3] + at[4]*bt[4]);
    ov0 += wv[13] * ( K1*(at[0]*bt[1] - at[1]*bt[0]) + K3*(at[3]*bt[2] - at[2]*bt[3]) + K1*(at[4]*bt[3] - at[3]*bt[4]) );
    ov1 += wv[13] * ( L4*(at[0]*bt[4] - at[4]*bt[0]) + K1*(at[1]*bt[3] - at[3]*bt[1]) );
    ov2 += wv[13] * ( K1*(at[3]*bt[0] - at[0]*bt[3]) + K3*(at[2]*bt[1] - at[1]*bt[2]) + K1*(at[4]*bt[1] - at[1]*bt[4]) );
    ot0 += wv[14] * ( G2*(at[2]*bt[0] + at[0]*bt[2]) - HH*(at[1]*bt[3] + at[3]*bt[1]) );
    ot1 += wv[14] * (-HH*(at[3]*bt[0] + at[0]*bt[3]) + HH*(at[1]*bt[4] + at[4]*bt[1]) - G1*(at[2]*bt[1] + at[1]*bt[2]) );
    ot2 += wv[14] * ( G2*(at[0]*bt[0] + at[4]*bt[4] - at[2]*bt[2]) - G1*(at[1]*bt[1] + at[3]*bt[3]) );
    ot3 += wv[14] * (-HH*(at[1]*bt[0] + at[0]*bt[1]) - HH*(at[3]*bt[4] + at[4]*bt[3]) - G1*(at[2]*bt[3] + at[3]*bt[2]) );
    ot4 += wv[14] * ( G2*(at[2]*bt[4] + at[4]*bt[2]) + HH*(at[1]*bt[1] - at[3]*bt[3]) );

    ms = os * 0.57735027f;
    mv[0] = ov0 * 0.40824829f; mv[1] = ov1 * 0.40824829f; mv[2] = ov2 * 0.40824829f;
    mt[0] = ot0 * 0.40824829f; mt[1] = ot1 * 0.40824829f; mt[2] = ot2 * 0.40824829f;
    mt[3] = ot3 * 0.40824829f; mt[4] = ot4 * 0.40824829f;
}

// ---------------------------------------------------------------------------
// CSR construction + fused permutation (slot order = dst-sorted).
// srcs PACKS src|dst<<16 (NODES=40000 < 2^16).
// ---------------------------------------------------------------------------
__global__ void deg_kernel(const int* __restrict__ eidx, int* __restrict__ deg)
{
    int e = blockIdx.x * 256 + threadIdx.x;
    if (e < EDGES) atomicAdd(&deg[eidx[EDGES + e]], 1);
}

__launch_bounds__(1024)
__global__ void scan_kernel(const int* __restrict__ deg, int* __restrict__ off,
                            int* __restrict__ cursor)
{
    __shared__ int part[1024];
    const int t = threadIdx.x;
    const int base = t * 40;     // threads 0..999 cover exactly 40000
    int v[40];
    if (t < 1000) {
        const int4* p4 = (const int4*)(deg + base);
        #pragma unroll
        for (int i = 0; i < 10; ++i) {
            int4 q = p4[i];
            v[4 * i + 0] = q.x; v[4 * i + 1] = q.y;
            v[4 * i + 2] = q.z; v[4 * i + 3] = q.w;
        }
    } else {
        #pragma unroll
        for (int i = 0; i < 40; ++i) v[i] = 0;
    }
    int loc[40];
    int s = 0;
    #pragma unroll
    for (int i = 0; i < 40; ++i) { loc[i] = s; s += v[i]; }
    part[t] = s;
    __syncthreads();
    for (int d = 1; d < 1024; d <<= 1) {
        int vv = (t >= d) ? part[t - d] : 0;
        __syncthreads();
        part[t] += vv;
        __syncthreads();
    }
    int tb = (t == 0) ? 0 : part[t - 1];
    if (t < 1000) {
        #pragma unroll
        for (int i = 0; i < 40; ++i) {
            off[base + i] = tb + loc[i];
            cursor[base + i] = tb + loc[i];
        }
    }
    if (t == 1023) off[NODES] = part[1023];
}

// build + permute fused: scatter packed src|dst and evp into CSR slot order
__global__ void build_kernel(const int* __restrict__ eidx, const float* __restrict__ ev,
                             int* __restrict__ cursor,
                             float* __restrict__ evp, int* __restrict__ srcs)
{
    int e = blockIdx.x * 256 + threadIdx.x;
    if (e < EDGES) {
        int dst = eidx[EDGES + e];
        int p = atomicAdd(&cursor[dst], 1);
        srcs[p] = (int)(((unsigned)eidx[e]) | ((unsigned)dst << 16));
        evp[p * 3 + 0] = ev[e * 3 + 0];
        evp[p * 3 + 1] = ev[e * 3 + 1];
        evp[p * 3 + 2] = ev[e * 3 + 2];
    }
}

// ---------------------------------------------------------------------------
// Layer 0: COMPACT output. me[i] = (wacc[p]*hs) * sh[i] is rank-1 per edge,
// so write only the 24 floats wacc[p]*hs (p=0..2, c=0..7) into the first 24
// slots of each edge's mbuf 72-block. Consumers (node0, tp_edge L1) rebuild
// me from compact + evp with IDENTICAL expression trees -> bit-identical.
// Write traffic: 184 MB -> 61 MB.
// ---------------------------------------------------------------------------
__launch_bounds__(256, 3)
__global__ void layer0_edge(const float* __restrict__ evp, const int* __restrict__ srcs,
                            const int* __restrict__ xs, const float* __restrict__ embw,
                            const float* __restrict__ w1, const float* __restrict__ b1,
                            const float* __restrict__ w2, const float* __restrict__ b2,
                            float* __restrict__ mbuf)
{
    __shared__ float emb_s[128 * 17];
    __shared__ float hid_s[128 * 68];
    __shared__ float w2t[24 * 68];
    const int tid = threadIdx.x;
    const int e0 = blockIdx.x * 128;

    for (int idx = tid; idx < 64 * 24; idx += 256) {
        int j = idx / 24, o = idx - j * 24;
        w2t[o * 68 + j] = w2[idx];
    }
    for (int idx = tid; idx < 2048; idx += 256) {
        int e = idx >> 4, i = idx & 15;
        const float* ep = evp + (size_t)(e0 + e) * 3;
        float ex = ep[0], ey = ep[1], ez = ep[2];
        float r = sqrtf(ex * ex + ey * ey + ez * ez + 1e-12f);
        float d = r * (17.0f / 3.0f) - (float)(i + 1);
        float f = 0.0f;
        if (fabsf(d) < 1.0f) f = 8.433572869f * __expf(-2.0f / (1.0f - d * d));
        emb_s[e * 17 + i] = f;
    }
    __syncthreads();

    {
        const int egp = tid >> 3;
        const int jb = (tid & 7) * 8;
        float acc2[4][8];
        #pragma unroll
        for (int el = 0; el < 4; ++el)
            #pragma unroll
            for (int k = 0; k < 8; ++k) acc2[el][k] = b1[jb + k];
        #pragma unroll
        for (int i = 0; i < 16; ++i) {
            float4 wa = *(const float4*)&w1[i * 64 + jb];
            float4 wb = *(const float4*)&w1[i * 64 + jb + 4];
            #pragma unroll
            for (int el = 0; el < 4; ++el) {
                float evv = emb_s[(egp * 4 + el) * 17 + i];
                acc2[el][0] += evv * wa.x; acc2[el][1] += evv * wa.y;
                acc2[el][2] += evv * wa.z; acc2[el][3] += evv * wa.w;
                acc2[el][4] += evv * wb.x; acc2[el][5] += evv * wb.y;
                acc2[el][6] += evv * wb.z; acc2[el][7] += evv * wb.w;
            }
        }
        #pragma unroll
        for (int el = 0; el < 4; ++el)
            #pragma unroll
            for (int k = 0; k < 8; ++k)
                hid_s[(egp * 4 + el) * 68 + jb + k] = silu_f(acc2[el][k]);
    }
    __syncthreads();

    const int c = tid & 7, g = (tid >> 3) & 7, wv_ = tid >> 6;
    float wacc[3][4];
    #pragma unroll
    for (int p = 0; p < 3; ++p) {
        float bb = b2[p * 8 + c];
        #pragma unroll
        for (int q = 0; q < 4; ++q) wacc[p][q] = bb;
    }
    for (int jb = 0; jb < 64; jb += 4) {
        float4 h4[4];
        #pragma unroll
        for (int q = 0; q < 4; ++q)
            h4[q] = *(const float4*)&hid_s[(wv_ * 32 + q * 8 + g) * 68 + jb];
        #pragma unroll
        for (int p = 0; p < 3; ++p) {
            float4 w4 = *(const float4*)&w2t[(p * 8 + c) * 68 + jb];
            #pragma unroll
            for (int q = 0; q < 4; ++q)
                wacc[p][q] += h4[q].x * w4.x + h4[q].y * w4.y + h4[q].z * w4.z + h4[q].w * w4.w;
        }
    }

    const int ebase = wv_ * 32 + g;
    #pragma unroll
    for (int q = 0; q < 4; ++q) {
        const int sl = e0 + ebase + 8 * q;
        const int sn = (int)((unsigned)srcs[sl] & 0xffffu);
        float hs = embw[xs[sn] * 8 + c];
        float* me = mbuf + (size_t)sl * 72;
        me[c]      = wacc[0][q] * hs;
        me[8 + c]  = wacc[1][q] * hs;
        me[16 + c] = wacc[2][q] * hs;
    }
}

// ---------------------------------------------------------------------------
// Layers 1/2 tp_edge: MFMA + half-tile + fused segmented agg (r5/r6-proven,
// BEST measured config: 666.4 us total).
//   compactB=1 (L1): b-operand rebuilt from layer0's compact 24-float record
//     + evp (bit-identical expressions). The full-72 m-write then overwrites
//     the same mbuf blocks — safe: per edge, compact-reads and 72-writes are
//     issued by the SAME wave (loads complete before stores issue; edges
//     disjoint across waves).
//   compactB=0 (L2): b-operand = full m from mbuf (L1 output), writeM=0.
// LDS: ws_t 32640 (emb/m_s aliased) + hid_s 16384 + dst_s 264 -> 3 blocks/CU.
// ---------------------------------------------------------------------------
__launch_bounds__(256, 3)
__global__ void tp_edge(const float* __restrict__ evp, const int* __restrict__ srcs,
                        const float* __restrict__ h,
                        const float* __restrict__ w1, const float* __restrict__ b1,
                        const float* __restrict__ w2, const float* __restrict__ b2,
                        float* __restrict__ mbuf, float* __restrict__ agg,
                        const int writeM, const int compactB)
{
    __shared__ float ws_t[120 * 68];            // half-tile w2-output / m_s spill
    __shared__ unsigned short hid_s[128 * 64];  // bf16 hidden, swizzled
    __shared__ int dst_s[66];
    float* emb_s = ws_t;                        // alias: emb dead before B writes

    const int tid = threadIdx.x;
    const int e0 = blockIdx.x * 128;

    // ---- phase A1: soft-onehot embedding ----
    for (int idx = tid; idx < 2048; idx += 256) {
        int e = idx >> 4, i = idx & 15;
        const float* ep = evp + (size_t)(e0 + e) * 3;
        float ex = ep[0], ey = ep[1], ez = ep[2];
        float r = sqrtf(ex * ex + ey * ey + ez * ez + 1e-12f);
        float d = r * (17.0f / 3.0f) - (float)(i + 1);
        float f = 0.0f;
        if (fabsf(d) < 1.0f) f = 8.433572869f * __expf(-2.0f / (1.0f - d * d));
        emb_s[e * 17 + i] = f;
    }
    __syncthreads();

    // ---- phase A2: layer-1 MLP (pk-fp32) -> silu -> bf16(RNE) -> swizzled hid_s ----
    {
        const int egp = tid >> 3;
        const int jb = (tid & 7) * 8;
        f32x2v acc2[2][8];
        #pragma unroll
        for (int pr = 0; pr < 2; ++pr)
            #pragma unroll
            for (int k = 0; k < 8; ++k) { float bb = b1[jb + k]; acc2[pr][k] = mk2(bb, bb); }
        #pragma unroll
        for (int i = 0; i < 16; ++i) {
            float4 wa = *(const float4*)&w1[i * 64 + jb];
            float4 wb = *(const float4*)&w1[i * 64 + jb + 4];
            #pragma unroll
            for (int pr = 0; pr < 2; ++pr) {
                f32x2v evv = mk2(emb_s[(egp * 4 + 2 * pr) * 17 + i],
                                 emb_s[(egp * 4 + 2 * pr + 1) * 17 + i]);
                acc2[pr][0] += evv * wa.x; acc2[pr][1] += evv * wa.y;
                acc2[pr][2] += evv * wa.z; acc2[pr][3] += evv * wa.w;
                acc2[pr][4] += evv * wb.x; acc2[pr][5] += evv * wb.y;
                acc2[pr][6] += evv * wb.z; acc2[pr][7] += evv * wb.w;
            }
        }
        #pragma unroll
        for (int pr = 0; pr < 2; ++pr) {
            #pragma unroll
            for (int u = 0; u < 2; ++u) {
                unsigned int us[8];
                #pragma unroll
                for (int k = 0; k < 8; ++k) {
                    unsigned int b = __float_as_uint(silu_f(acc2[pr][k][u]));
                    b += 0x7fffu + ((b >> 16) & 1u);
                    us[k] = b >> 16;
                }
                uint4 pk;
                pk.x = us[0] | (us[1] << 16);
                pk.y = us[2] | (us[3] << 16);
                pk.z = us[4] | (us[5] << 16);
                pk.w = us[6] | (us[7] << 16);
                int rr = egp * 4 + 2 * pr + u;
                *(uint4*)&hid_s[rr * 64 + (jb ^ ((rr & 7) << 3))] = pk;
            }
        }
    }
    __syncthreads();

    // ---- B-operand fragments: w2 hi/lo bf16 split, registers (L2-hot) ----
    const int l  = tid & 63;
    const int wq = tid >> 6;
    const int lr = l & 15;
    const int lg = l >> 4;

    short8v bhi[2][2], blo[2][2];   // [n2][ks]
    #pragma unroll
    for (int n2 = 0; n2 < 2; ++n2) {
        int col  = (2 * wq + n2) * 16 + lr;
        int colc = col < 120 ? col : 119;
        #pragma unroll
        for (int ks = 0; ks < 2; ++ks) {
            short8v hv, lv;
            #pragma unroll
            for (int j = 0; j < 8; ++j) {
                int k = ks * 32 + lg * 8 + j;
                float v = w2[k * 120 + colc];
                if (col >= 120) v = 0.0f;
                unsigned bb = __float_as_uint(v);
                unsigned rh = bb + 0x7fffu + ((bb >> 16) & 1u);
                float hf = __uint_as_float((rh >> 16) << 16);
                unsigned bl = __float_as_uint(v - hf);
                bl += 0x7fffu + ((bl >> 16) & 1u);
                hv[j] = (short)(rh >> 16);
                lv[j] = (short)(bl >> 16);
            }
            bhi[n2][ks] = hv;
            blo[n2][ks] = lv;
        }
    }

    const int c = tid & 7, g = (tid >> 3) & 7, wv_ = tid >> 6;
    const int ebh = wv_ * 16 + g;   // phase-C local edge base, pair +0/+8

    #pragma unroll
    for (int half = 0; half < 2; ++half) {
        // ---- phase B: MFMA for 64 edges [64*half, 64*half+64) -> ws_t ----
        #pragma unroll
        for (int mm = 0; mm < 4; ++mm) {
            int e  = 64 * half + 16 * mm + lr;
            int sw = (e & 7) << 3;
            short8v a0 = *(const short8v*)&hid_s[e * 64 + ((lg * 8) ^ sw)];
            short8v a1 = *(const short8v*)&hid_s[e * 64 + ((32 + lg * 8) ^ sw)];
            #pragma unroll
            for (int n2 = 0; n2 < 2; ++n2) {
                int col = (2 * wq + n2) * 16 + lr;
                float bias = (col < 120) ? b2[col] : 0.0f;
                f32x4v acc;
                acc[0] = bias; acc[1] = bias; acc[2] = bias; acc[3] = bias;
                acc = __builtin_amdgcn_mfma_f32_16x16x32_bf16(a0, bhi[n2][0], acc, 0, 0, 0);
                acc = __builtin_amdgcn_mfma_f32_16x16x32_bf16(a1, bhi[n2][1], acc, 0, 0, 0);
                acc = __builtin_amdgcn_mfma_f32_16x16x32_bf16(a0, blo[n2][0], acc, 0, 0, 0);
                acc = __builtin_amdgcn_mfma_f32_16x16x32_bf16(a1, blo[n2][1], acc, 0, 0, 0);
                if (col < 120)
                    *(f32x4v*)&ws_t[col * 68 + 16 * mm + lg * 4] = acc;
            }
        }
        __syncthreads();

        // ---- phase C: tp_uuu for this half's 64 edges ----
        {
            const int eA = e0 + 64 * half + ebh;
            const int eB = eA + 8;
            const unsigned pkA = (unsigned)srcs[eA], pkB = (unsigned)srcs[eB];
            const int snA = (int)(pkA & 0xffffu), snB = (int)(pkB & 0xffffu);
            const float* hn0 = h + (size_t)snA * 72 + c * 9;
            const float* hn1 = h + (size_t)snB * 72 + c * 9;

            f32x2v as = mk2(hn0[0], hn1[0]);
            f32x2v av[3], at[5], bv[3], bt[5], bs;
            #pragma unroll
            for (int i = 0; i < 3; ++i) av[i] = mk2(hn0[1 + i], hn1[1 + i]);
            #pragma unroll
            for (int i = 0; i < 5; ++i) at[i] = mk2(hn0[4 + i], hn1[4 + i]);

            if (compactB) {
                // rebuild layer0's me from compact record + evp (bit-identical)
                float w0A = mbuf[(size_t)eA * 72 + c];
                float w1A = mbuf[(size_t)eA * 72 + 8 + c];
                float w2A = mbuf[(size_t)eA * 72 + 16 + c];
                float w0B = mbuf[(size_t)eB * 72 + c];
                float w1B = mbuf[(size_t)eB * 72 + 8 + c];
                float w2B = mbuf[(size_t)eB * 72 + 16 + c];
                const float* epA = evp + (size_t)eA * 3;
                const float* epB = evp + (size_t)eB * 3;
                float exA = epA[0], eyA = epA[1], ezA = epA[2];
                float exB = epB[0], eyB = epB[1], ezB = epB[2];
                float rA = sqrtf(exA * exA + eyA * eyA + ezA * ezA + 1e-12f);
                float rB = sqrtf(exB * exB + eyB * eyB + ezB * ezB + 1e-12f);
                float iA = 1.0f / rA, iB = 1.0f / rB;
                float xA = exA * iA, yA = eyA * iA, zA = ezA * iA;
                float xB = exB * iB, yB = eyB * iB, zB = ezB * iB;
                const float c3 = 1.7320508f, c15 = 3.8729833f, c5 = 2.2360680f;
                bs = mk2(silu_f(w0A), silu_f(w0B));
                bv[0] = mk2(w1A * (c3 * yA), w1B * (c3 * yB));
                bv[1] = mk2(w1A * (c3 * zA), w1B * (c3 * zB));
                bv[2] = mk2(w1A * (c3 * xA), w1B * (c3 * xB));
                bt[0] = mk2(w2A * (c15 * xA * yA), w2B * (c15 * xB * yB));
                bt[1] = mk2(w2A * (c15 * yA * zA), w2B * (c15 * yB * zB));
                bt[2] = mk2(w2A * (0.5f * c5 * (3.f * zA * zA - 1.f)),
                            w2B * (0.5f * c5 * (3.f * zB * zB - 1.f)));
                bt[3] = mk2(w2A * (c15 * xA * zA), w2B * (c15 * xB * zB));
                bt[4] = mk2(w2A * (0.5f * c15 * (xA * xA - yA * yA)),
                            w2B * (0.5f * c15 * (xB * xB - yB * yB)));
            } else {
                const float* me0 = mbuf + (size_t)eA * 72 + c * 9;
                const float* me1 = mbuf + (size_t)eB * 72 + c * 9;
                bs = mk2(silu_f(me0[0]), silu_f(me1[0]));
                #pragma unroll
                for (int i = 0; i < 3; ++i) bv[i] = mk2(me0[1 + i], me1[1 + i]);
                #pragma unroll
                for (int i = 0; i < 5; ++i) bt[i] = mk2(me0[4 + i], me1[4 + i]);
            }

            f32x2v wvv[15];
            #pragma unroll
            for (int p = 0; p < 15; ++p)
                wvv[p] = mk2(ws_t[(p * 8 + c) * 68 + ebh],
                             ws_t[(p * 8 + c) * 68 + ebh + 8]);

            f32x2v ms, mv[3], mt[5];
            tp_uuu2(wvv, as, av, at, bs, bv, bt, ms, mv, mt);

            if (writeM) {
                float* mo0 = mbuf + (size_t)eA * 72 + c * 9;
                float* mo1 = mbuf + (size_t)eB * 72 + c * 9;
                mo0[0] = ms[0]; mo1[0] = ms[1];
                #pragma unroll
                for (int i = 0; i < 3; ++i) { mo0[1 + i] = mv[i][0]; mo1[1 + i] = mv[i][1]; }
                #pragma unroll
                for (int i = 0; i < 5; ++i) { mo0[4 + i] = mt[i][0]; mo1[4 + i] = mt[i][1]; }
            }

            // dst window [e0+64h, e0+64h+64]; sentinel past array end
            if (tid <= 64) {
                int gs = e0 + 64 * half + tid;
                dst_s[tid] = (gs < EDGES) ? (int)((unsigned)srcs[gs] >> 16) : -1;
            }
            __syncthreads();   // wvv reads done + dst_s visible -> ws_t reusable

            // spill m into m_s[64][72] (ws_t region)
            float* m_s = ws_t;
            const int lA = ebh, lB = ebh + 8;
            m_s[lA * 72 + c * 9] = ms[0]; m_s[lB * 72 + c * 9] = ms[1];
            #pragma unroll
            for (int i = 0; i < 3; ++i) {
                m_s[lA * 72 + c * 9 + 1 + i] = mv[i][0];
                m_s[lB * 72 + c * 9 + 1 + i] = mv[i][1];
            }
            #pragma unroll
            for (int i = 0; i < 5; ++i) {
                m_s[lA * 72 + c * 9 + 4 + i] = mt[i][0];
                m_s[lB * 72 + c * 9 + 4 + i] = mt[i][1];
            }
            __syncthreads();

            // segmented reduce: comp = t%72, 3 slot-subranges, slot order
            if (tid < 216) {
                const int seg  = tid / 72;
                const int comp = tid - seg * 72;
                const int p0 = (seg == 0) ? 0  : ((seg == 1) ? 22 : 43);
                const int p1 = (seg == 0) ? 22 : ((seg == 1) ? 43 : 64);
                float sum = 0.f;
                int cur = dst_s[p0];
                for (int p = p0; p < p1; ++p) {
                    sum += m_s[p * 72 + comp];
                    int nxt = dst_s[p + 1];
                    if (nxt != cur) {
                        atomicAdd(&agg[(size_t)cur * 72 + comp], sum);
                        sum = 0.f; cur = nxt;
                    }
                }
                if (cur >= 0) atomicAdd(&agg[(size_t)cur * 72 + comp], sum);
            }
        }
        if (half == 0) __syncthreads();   // m_s reads done before B overwrites
    }
}

// ---------------------------------------------------------------------------
// node0: rebuilds layer0's me from the compact record + evp (bit-identical
// expressions, slot order preserved). FETCH: 184 MB -> ~69 MB.
// ---------------------------------------------------------------------------
__global__ void node0(const int* __restrict__ xs, const float* __restrict__ embw,
                      const float* __restrict__ lin0, const float* __restrict__ mbuf,
                      const float* __restrict__ evp,
                      const int* __restrict__ off, float* __restrict__ h)
{
    int idx = blockIdx.x * 256 + threadIdx.x;
    int n = idx >> 3, c = idx & 7;
    int xb = xs[n] * 8;
    float dot = 0.f;
    #pragma unroll
    for (int d = 0; d < 8; ++d) dot += embw[xb + d] * lin0[d * 8 + c];

    float an[9];
    #pragma unroll
    for (int i = 0; i < 9; ++i) an[i] = 0.f;
    const float c3 = 1.7320508f, c15 = 3.8729833f, c5 = 2.2360680f;
    const int beg = off[n], end = off[n + 1];
    for (int p = beg; p < end; ++p) {
        float w0 = mbuf[(size_t)p * 72 + c];
        float w1 = mbuf[(size_t)p * 72 + 8 + c];
        float w2 = mbuf[(size_t)p * 72 + 16 + c];
        const float* ep = evp + (size_t)p * 3;
        float ex = ep[0], ey = ep[1], ez = ep[2];
        float r = sqrtf(ex * ex + ey * ey + ez * ez + 1e-12f);
        float inv = 1.0f / r;
        float x = ex * inv, y = ey * inv, z = ez * inv;
        an[0] += w0;
        an[1] += w1 * (c3 * y);
        an[2] += w1 * (c3 * z);
        an[3] += w1 * (c3 * x);
        an[4] += w2 * (c15 * x * y);
        an[5] += w2 * (c15 * y * z);
        an[6] += w2 * (0.5f * c5 * (3.f * z * z - 1.f));
        an[7] += w2 * (c15 * x * z);
        an[8] += w2 * (0.5f * c15 * (x * x - y * y));
    }

    float* hn = h + (size_t)n * 72 + c * 9;
    hn[0] = silu_f(an[0] * 0.25f + dot * 0.35355339f);
    #pragma unroll
    for (int i = 1; i < 9; ++i) hn[i] = an[i] * 0.25f;
}

// reads agg (in-place safe: per-thread reads then writes same 9 floats)
__global__ void node12(const float* __restrict__ hin, const float* __restrict__ lin,
                       const float* __restrict__ agg, float* __restrict__ hout)
{
    int idx = blockIdx.x * 256 + threadIdx.x;
    int n = idx >> 3, d = idx & 7;

    float an[9];
    #pragma unroll
    for (int i = 0; i < 9; ++i) an[i] = agg[(size_t)n * 72 + d * 9 + i];

    const float* hn = hin + (size_t)n * 72;
    float* ho = hout + (size_t)n * 72 + d * 9;

    float s = 0.f;
    #pragma unroll
    for (int c = 0; c < 8; ++c) s += hn[c * 9] * lin[c * 8 + d];
    ho[0] = silu_f(s * 0.35355339f + an[0] * 0.25f);
    #pragma unroll
    for (int i = 0; i < 3; ++i) {
        float v = 0.f;
        #pragma unroll
        for (int c = 0; c < 8; ++c) v += hn[c * 9 + 1 + i] * lin[64 + c * 8 + d];
        ho[1 + i] = v * 0.35355339f + an[1 + i] * 0.25f;
    }
    #pragma unroll
    for (int i = 0; i < 5; ++i) {
        float t = 0.f;
        #pragma unroll
        for (int c = 0; c < 8; ++c) t += hn[c * 9 + 4 + i] * lin[128 + c * 8 + d];
        ho[4 + i] = t * 0.35355339f + an[4 + i] * 0.25f;
    }
}

// Fused final node update + output head, reading agg instead of mbuf scan
__global__ void node12_out(const float* __restrict__ hin, const float* __restrict__ lin,
                           const float* __restrict__ agg,
                           const float* __restrict__ outw, float* __restrict__ out)
{
    __shared__ float hrec[32][72];
    int idx = blockIdx.x * 256 + threadIdx.x;
    int n = idx >> 3, d = idx & 7;
    int nl = threadIdx.x >> 3;

    float an[9];
    #pragma unroll
    for (int i = 0; i < 9; ++i) an[i] = agg[(size_t)n * 72 + d * 9 + i];

    const float* hn = hin + (size_t)n * 72;
    float* ho = &hrec[nl][d * 9];

    float s = 0.f;
    #pragma unroll
    for (int c = 0; c < 8; ++c) s += hn[c * 9] * lin[c * 8 + d];
    ho[0] = silu_f(s * 0.35355339f + an[0] * 0.25f);
    #pragma unroll
    for (int i = 0; i < 3; ++i) {
        float v = 0.f;
        #pragma unroll
        for (int c = 0; c < 8; ++c) v += hn[c * 9 + 1 + i] * lin[64 + c * 8 + d];
        ho[1 + i] = v * 0.35355339f + an[1 + i] * 0.25f;
    }
    #pragma unroll
    for (int i = 0; i < 5; ++i) {
        float t = 0.f;
        #pragma unroll
        for (int c = 0; c < 8; ++c) t += hn[c * 9 + 4 + i] * lin[128 + c * 8 + d];
        ho[4 + i] = t * 0.35355339f + an[4 + i] * 0.25f;
    }
    __syncthreads();

    const float* hr = &hrec[nl][0];
    float sv[8], vv[24], tv[40];
    #pragma unroll
    for (int i = 0; i < 8; ++i) {
        sv[i] = hr[i * 9];
        #pragma unroll
        for (int q = 0; q < 3; ++q) vv[i * 3 + q] = hr[i * 9 + 1 + q];
        #pragma unroll
        for (int q = 0; q < 5; ++q) tv[i * 5 + q] = hr[i * 9 + 4 + q];
    }
    float acc = 0.f;
    #pragma unroll
    for (int i = 0; i < 8; ++i) {
        #pragma unroll
        for (int j = 0; j < 8; ++j) {
            float dv = vv[i*3+0]*vv[j*3+0] + vv[i*3+1]*vv[j*3+1] + vv[i*3+2]*vv[j*3+2];
            float dt = tv[i*5+0]*tv[j*5+0] + tv[i*5+1]*tv[j*5+1] + tv[i*5+2]*tv[j*5+2]
                     + tv[i*5+3]*tv[j*5+3] + tv[i*5+4]*tv[j*5+4];
            int o = (i * 8 + j) * 8 + d;
            acc += sv[i] * sv[j] * outw[o]
                 + dv * 0.57735027f * outw[512 + o]
                 + dt * 0.44721360f * outw[1024 + o];
        }
    }
    out[n * 8 + d] = acc * 0.072168784f;
}

// ---------------------------------------------------------------------------
extern "C" void kernel_launch(void* const* d_in, const int* in_sizes, int n_in,
                              void* d_out, int out_size, void* d_ws, size_t ws_size,
                              hipStream_t stream)
{
    const int*   x    = (const int*)  d_in[0];
    const int*   eidx = (const int*)  d_in[1];
    const float* ev   = (const float*)d_in[2];
    const float* embw = (const float*)d_in[3];
    const float* lin0 = (const float*)d_in[4];
    const float* lin1 = (const float*)d_in[5];
    const float* lin2 = (const float*)d_in[6];
    const float* outw = (const float*)d_in[7];
    const float* r0w1 = (const float*)d_in[8];
    const float* r0b1 = (const float*)d_in[9];
    const float* r0w2 = (const float*)d_in[10];
    const float* r0b2 = (const float*)d_in[11];
    const float* r1w1 = (const float*)d_in[12];
    const float* r1b1 = (const float*)d_in[13];
    const float* r1w2 = (const float*)d_in[14];
    const float* r1b2 = (const float*)d_in[15];
    const float* r2w1 = (const float*)d_in[16];
    const float* r2b1 = (const float*)d_in[17];
    const float* r2w2 = (const float*)d_in[18];
    const float* r2b2 = (const float*)d_in[19];

    float* mbuf = (float*)d_ws;                          // EDGES*72 f32
    float* hA   = mbuf + (size_t)EDGES * 72;             // NODES*72
    float* hB   = hA + (size_t)NODES * 72;               // NODES*72
    float* evp  = hB + (size_t)NODES * 72;               // EDGES*3
    int*   deg    = (int*)(evp + (size_t)EDGES * 3);     // NODES
    int*   off    = deg + NODES;                         // NODES+1
    int*   cursor = off + NODES + 1;                     // NODES
    int*   srcs   = cursor + NODES;                      // EDGES (src|dst<<16)

    const int EBI = (EDGES + 255) / 256;
    const int EB  = EDGES / 128;
    const int NBK = NODES * 8 / 256;
    const size_t HBYTES = (size_t)NODES * 72 * sizeof(float);

    // CSR build + fused permutation
    hipMemsetAsync(deg, 0, NODES * sizeof(int), stream);
    hipMemsetAsync(hB, 0, HBYTES, stream);               // L1 agg target
    deg_kernel<<<EBI, 256, 0, stream>>>(eidx, deg);
    scan_kernel<<<1, 1024, 0, stream>>>(deg, off, cursor);
    build_kernel<<<EBI, 256, 0, stream>>>(eidx, ev, cursor, evp, srcs);

    // Layer 0 (compact m record)
    layer0_edge<<<EB, 256, 0, stream>>>(evp, srcs, x, embw, r0w1, r0b1, r0w2, r0b2, mbuf);
    node0<<<NBK, 256, 0, stream>>>(x, embw, lin0, mbuf, evp, off, hA);

    // Layer 1: compact b-operand; aggregates into hB; node12 transforms in place
    tp_edge<<<EB, 256, 0, stream>>>(evp, srcs, hA, r1w1, r1b1, r1w2, r1b2, mbuf, hB, 1, 1);
    node12<<<NBK, 256, 0, stream>>>(hA, lin1, hB, hB);

    // Layer 2: full-m b-operand; hA dead after node12 -> reuse as agg; no mbuf write
    hipMemsetAsync(hA, 0, HBYTES, stream);
    tp_edge<<<EB, 256, 0, stream>>>(evp, srcs, hB, r2w1, r2b1, r2w2, r2b2, mbuf, hA, 0, 0);
    node12_out<<<NBK, 256, 0, stream>>>(hB, lin2, hA, outw, (float*)d_out);
}